// Round 12
// baseline (453.004 us; speedup 1.0000x reference)
//
#include <hip/hip_runtime.h>
#include <hip/hip_bf16.h>

#define LN_EPS 1e-6f

typedef __attribute__((ext_vector_type(8))) short bf16x8;
typedef __attribute__((ext_vector_type(4))) float fx4;

struct U8 { union { bf16x8 v; uint2 p[2]; }; };

__device__ __forceinline__ unsigned short f2bf(float f) {
    union { __hip_bfloat16 b; unsigned short u; } cv;
    cv.b = __float2bfloat16(f);
    return cv.u;
}

// ---------- fused prep: pad detect + pooled memset + conv weight repack + tail weight pack ----------
// block 0: pad; blocks [1,129): pooled=0; [129,209): wtb; [209,4402): wpk
__global__ __launch_bounds__(256) void k_prep(
    const unsigned char* __restrict__ pad,
    const float* __restrict__ w1, const float* __restrict__ w0,
    const float* __restrict__ qkvw, const float* __restrict__ ow,
    const float* __restrict__ upw, const float* __restrict__ dww,
    const float* __restrict__ pw, const float* __restrict__ hw,
    float* __restrict__ padf, unsigned short* __restrict__ wtb,
    unsigned short* __restrict__ wpk, float* __restrict__ pooled)
{
    __shared__ int cnt;
    const int bid = blockIdx.x, t = threadIdx.x;
    if (bid == 0) {
        if (t == 0) cnt = 0;
        __syncthreads();
        int c = 0;
        if (pad[t]) c++;
        if (pad[t + 256]) c++;
        if (c) atomicAdd(&cnt, c);
        __syncthreads();
        bool asU8 = cnt > 256;
        for (int i = t; i < 512; i += 256)
            padf[i] = asU8 ? (pad[i] ? 1.f : 0.f) : (((const int*)pad)[i] ? 1.f : 0.f);
    } else if (bid < 129) {
        pooled[(bid - 1) * 256 + t] = 0.f;
    } else if (bid < 209) {
        int idx = (bid - 129) * 256 + t;
        if (idx < 18432) {
            int j  = idx & 7;
            int kg = (idx >> 3) & 3;
            int co = (idx >> 5) & 63;
            int tp = idx >> 11;
            wtb[idx] = f2bf(w1[((size_t)tp * 32 + kg * 8 + j) * 64 + co]);
        } else {
            int r = idx - 18432;
            int ch = r >> 6, k = r & 63;
            float v = 0.f;
            if (k < 36) v = w0[(size_t)k * 32 + ch];
            wtb[idx] = f2bf(v);
        }
    } else {
        int idx = (bid - 209) * 256 + t;
        if (idx >= 1073152) return;
        float v;
        if (idx < 393216) {
            int l = idx / 196608, rm = idx % 196608, n = rm >> 8, k = rm & 255;
            v = qkvw[((size_t)l * 256 + k) * 768 + n];
        } else if (idx < 524288) {
            int r = idx - 393216, l = r >> 16, rm = r & 65535, n = rm >> 8, k = rm & 255;
            v = ow[((size_t)l * 256 + k) * 256 + n];
        } else if (idx < 786432) {
            int r = idx - 524288, l = r >> 17, rm = r & 131071, n = rm >> 8, k = rm & 255;
            v = upw[((size_t)l * 256 + k) * 512 + n];
        } else if (idx < 1048576) {
            int r = idx - 786432, l = r >> 17, rm = r & 131071, n = rm >> 9, k = rm & 511;
            v = dww[((size_t)l * 512 + k) * 256 + n];
        } else if (idx < 1064960) {
            int r = idx - 1048576, n = r >> 6, k = r & 63;
            v = pw[k * 256 + n];
        } else {
            int r = idx - 1064960, n = r >> 8, k = r & 255;
            v = (n < 18) ? hw[(size_t)k * 18 + n] : 0.f;
        }
        wpk[idx] = f2bf(v);
    }
}

// ---------- fused conv0+conv1 + LN + ReLU + mean-pool ----------
// Occupancy build: 3-row block (LDS 33.4 KB -> 4 blocks/CU), (256,4) = 4 waves/SIMD,
// phase-2 acc split over pixels (acc[4][2] = 32 AGPR, 2 passes) to fit 128-reg budget.
// Phase 0: stage x rows y0-2..y0+4 bf16 -> xs[7][86][4].
// Phase 1 (swapped): conv0 MFMA over 420 px (5 rows) -> At[4][5][86][8]; incremental addr.
// Phase 2+3: two 2-n-tile passes of conv1 MFMA + LN(64) + ReLU + pool, streamed per m.
__global__ __launch_bounds__(256, 4) void k_conv1(
    const float* __restrict__ x, const unsigned short* __restrict__ wtb,
    const float* __restrict__ c0b, const float* __restrict__ l0s, const float* __restrict__ l0b,
    const float* __restrict__ bias, const float* __restrict__ lns, const float* __restrict__ lnb,
    float* __restrict__ pooled)
{
    __shared__ __align__(16) unsigned short At[4][5][86][8];   // 27520 B
    __shared__ __align__(16) unsigned short xs[7][86][4];      // 4816 B
    __shared__ __align__(16) float pool_w[4][64];              // 1024 B
    const int tid = threadIdx.x;
    const int img = blockIdx.x / 28;
    const int rg  = blockIdx.x - img * 28;
    const int y0  = rg * 3;

    const int lane = tid & 63;
    const int wv = tid >> 6;
    const int lo = lane & 15;
    const int kg = lane >> 4;

    // ---- phase 0: stage x (7 rows, bf16, halo-padded) + zero At/xs halo cols ----
    if (tid >= 64 && tid < 104) {
        int z = tid - 64;                   // 40: 4 granules x 5 rows x 2 sides
        int zk = z / 10, rem = z - zk * 10, zr = rem >> 1, side = rem & 1;
        *reinterpret_cast<uint4*>(&At[zk][zr][side ? 85 : 0][0]) = (uint4){0, 0, 0, 0};
    }
    if (tid >= 104 && tid < 118) {
        int z = tid - 104, row = z >> 1, side = z & 1;
        *reinterpret_cast<uint2*>(&xs[row][side ? 85 : 0][0]) = (uint2){0, 0};
    }
    for (int i = tid; i < 588; i += 256) {
        int row = i / 84, c = i - row * 84;
        int gy = y0 - 2 + row;
        float4 v = (float4){0.f, 0.f, 0.f, 0.f};
        if (gy >= 0 && gy < 84)
            v = *reinterpret_cast<const float4*>(x + ((size_t)img * 7056 + gy * 84 + c) * 4);
        unsigned l32 = (unsigned)f2bf(v.x) | ((unsigned)f2bf(v.y) << 16);
        unsigned h32 = (unsigned)f2bf(v.z) | ((unsigned)f2bf(v.w) << 16);
        *reinterpret_cast<uint2*>(&xs[row][c + 1][0]) = (uint2){l32, h32};
    }
    __syncthreads();

    // ---- phase 1: conv0 via MFMA (operand-swapped) -> At (5 rows, 420 px, 27 tiles) ----
    {
        const unsigned short* wc0 = wtb + 18432;
        bf16x8 W0[2], W1[2];
        #pragma unroll
        for (int m = 0; m < 2; ++m) {
            W0[m] = *reinterpret_cast<const bf16x8*>(wc0 + (m * 16 + lo) * 64 + kg * 8);
            W1[m] = *reinterpret_cast<const bf16x8*>(wc0 + (m * 16 + lo) * 64 + 32 + kg * 8);
        }
        float cb[2][4], sg[2][4], bg[2][4];
        #pragma unroll
        for (int m = 0; m < 2; ++m)
            #pragma unroll
            for (int r = 0; r < 4; ++r) {
                int c = m * 16 + kg * 4 + r;
                cb[m][r] = c0b[c]; sg[m][r] = l0s[c]; bg[m][r] = l0b[c];
            }
        const int t0 = 2 * kg, t1 = 2 * kg + 1;
        const int dy0 = t0 / 3, dx0 = t0 % 3, dy1 = t1 / 3, dx1 = t1 % 3;
        const unsigned short* xsb = &xs[0][0][0];

        // incremental pixel addressing: px = it*64 + wv*16 + lo; step 64 < 84 -> single wrap
        int r5 = 0, col = wv * 16 + lo;
        for (int it = 0; it < 7; ++it) {
            int tb = it * 4 + wv;
            if (tb >= 27) break;
            bool ok = r5 < 5;                       // px < 420
            int r5c = ok ? r5 : 4, colc = ok ? col : 83;
            U8 a0u, a1u;
            a0u.p[0] = *reinterpret_cast<const uint2*>(xsb + ((r5c + dy0) * 86 + colc + dx0) * 4);
            a0u.p[1] = *reinterpret_cast<const uint2*>(xsb + ((r5c + dy1) * 86 + colc + dx1) * 4);
            if (kg == 0)
                a1u.p[0] = *reinterpret_cast<const uint2*>(xsb + ((r5c + 2) * 86 + colc + 2) * 4);
            else
                a1u.p[0] = (uint2){0, 0};
            a1u.p[1] = (uint2){0, 0};

            fx4 c2[2];
            c2[0] = (fx4){0.f, 0.f, 0.f, 0.f};
            c2[1] = (fx4){0.f, 0.f, 0.f, 0.f};
            c2[0] = __builtin_amdgcn_mfma_f32_16x16x32_bf16(W0[0], a0u.v, c2[0], 0, 0, 0);
            c2[0] = __builtin_amdgcn_mfma_f32_16x16x32_bf16(W1[0], a1u.v, c2[0], 0, 0, 0);
            c2[1] = __builtin_amdgcn_mfma_f32_16x16x32_bf16(W0[1], a0u.v, c2[1], 0, 0, 0);
            c2[1] = __builtin_amdgcn_mfma_f32_16x16x32_bf16(W1[1], a1u.v, c2[1], 0, 0, 0);

            float v[2][4], s = 0.f, q = 0.f;
            #pragma unroll
            for (int m = 0; m < 2; ++m)
                #pragma unroll
                for (int r = 0; r < 4; ++r) {
                    v[m][r] = c2[m][r] + cb[m][r];
                    s += v[m][r]; q += v[m][r] * v[m][r];
                }
            s += __shfl_xor(s, 16); q += __shfl_xor(q, 16);
            s += __shfl_xor(s, 32); q += __shfl_xor(q, 32);
            float mn = s * (1.f / 32.f);
            float inv = rsqrtf(q * (1.f / 32.f) - mn * mn + LN_EPS);

            if (ok) {
                int yA = y0 - 1 + r5c;
                bool gv = (unsigned)yA < 84u;
                #pragma unroll
                for (int m = 0; m < 2; ++m) {
                    uint2 pk = (uint2){0, 0};
                    if (gv) {
                        unsigned short o0 = f2bf(fmaxf((v[m][0] - mn) * inv * sg[m][0] + bg[m][0], 0.f));
                        unsigned short o1 = f2bf(fmaxf((v[m][1] - mn) * inv * sg[m][1] + bg[m][1], 0.f));
                        unsigned short o2 = f2bf(fmaxf((v[m][2] - mn) * inv * sg[m][2] + bg[m][2], 0.f));
                        unsigned short o3 = f2bf(fmaxf((v[m][3] - mn) * inv * sg[m][3] + bg[m][3], 0.f));
                        pk.x = (unsigned)o0 | ((unsigned)o1 << 16);
                        pk.y = (unsigned)o2 | ((unsigned)o3 << 16);
                    }
                    *reinterpret_cast<uint2*>(&At[2 * m + (kg >> 1)][r5c][colc + 1][(kg & 1) * 4]) = pk;
                }
            }
            col += 64;
            if (col >= 84) { col -= 84; r5 += 1; }
        }
    }
    __syncthreads();

    // ---- phases 2+3: two 2-n-tile passes (acc[4][2] = 32 AGPR), epilogue streamed per m ----
    const unsigned short* Abase = &At[0][0][0][0];
    #pragma unroll
    for (int p = 0; p < 2; ++p) {
        int abase[2];
        #pragma unroll
        for (int n = 0; n < 2; ++n) {
            int pl = wv * 64 + (p * 2 + n) * 16 + lo;
            if (pl > 251) pl = 251;
            int rl = pl / 84;
            int c = pl - rl * 84;
            abase[n] = ((kg * 5 + rl) * 86 + c) * 8;
        }

        fx4 acc[4][2];   // acc[m][n]: channels m*16+kg*4+rg, pixel (p*2+n)*16+lo
        #pragma unroll
        for (int m = 0; m < 4; ++m) {
            acc[m][0] = (fx4){0.f, 0.f, 0.f, 0.f};
            acc[m][1] = (fx4){0.f, 0.f, 0.f, 0.f};
        }

        #pragma unroll
        for (int dy = 0; dy < 3; ++dy) {
            #pragma unroll
            for (int dx = 0; dx < 3; ++dx) {
                const int t = dy * 3 + dx;
                bf16x8 Wf[4];
                #pragma unroll
                for (int m = 0; m < 4; ++m)
                    Wf[m] = *reinterpret_cast<const bf16x8*>(
                        wtb + (size_t)((t * 64 + m * 16 + lo) * 4 + kg) * 8);
                #pragma unroll
                for (int n = 0; n < 2; ++n) {
                    bf16x8 Pf = *reinterpret_cast<const bf16x8*>(Abase + abase[n] + (dy * 86 + dx) * 8);
                    #pragma unroll
                    for (int m = 0; m < 4; ++m)
                        acc[m][n] = __builtin_amdgcn_mfma_f32_16x16x32_bf16(Wf[m], Pf, acc[m][n], 0, 0, 0);
                }
            }
        }

        // stats pass: bias (in-place) + per-pixel sums
        float s2[2] = {0.f, 0.f}, q2[2] = {0.f, 0.f};
        #pragma unroll
        for (int m = 0; m < 4; ++m) {
            float4 cbv = *reinterpret_cast<const float4*>(bias + m * 16 + kg * 4);
            #pragma unroll
            for (int n = 0; n < 2; ++n)
                #pragma unroll
                for (int r = 0; r < 4; ++r) {
                    float val = acc[m][n][r] + (&cbv.x)[r];
                    acc[m][n][r] = val;
                    s2[n] += val; q2[n] += val * val;
                }
        }
        float mn2[2], iv2[2], pv2[2];
        #pragma unroll
        for (int n = 0; n < 2; ++n) {
            float s = s2[n], q = q2[n];
            s += __shfl_xor(s, 16); q += __shfl_xor(q, 16);
            s += __shfl_xor(s, 32); q += __shfl_xor(q, 32);
            float mn = s * (1.f / 64.f);
            mn2[n] = mn;
            iv2[n] = rsqrtf(q * (1.f / 64.f) - mn * mn + LN_EPS);
            pv2[n] = (wv * 64 + (p * 2 + n) * 16 + lo < 252) ? 1.f : 0.f;
        }
        // streamed per-m: normalize + pool + butterfly + LDS RMW
        #pragma unroll
        for (int m = 0; m < 4; ++m) {
            float4 sgv = *reinterpret_cast<const float4*>(lns + m * 16 + kg * 4);
            float4 bgv = *reinterpret_cast<const float4*>(lnb + m * 16 + kg * 4);
            float pm[4] = {0.f, 0.f, 0.f, 0.f};
            #pragma unroll
            for (int n = 0; n < 2; ++n)
                #pragma unroll
                for (int r = 0; r < 4; ++r) {
                    float o = fmaxf((acc[m][n][r] - mn2[n]) * iv2[n] * (&sgv.x)[r] + (&bgv.x)[r], 0.f);
                    pm[r] = fmaf(o, pv2[n], pm[r]);
                }
            #pragma unroll
            for (int off = 1; off < 16; off <<= 1)
                #pragma unroll
                for (int r = 0; r < 4; ++r)
                    pm[r] += __shfl_xor(pm[r], off);
            if (lo == 0) {
                float4 pk;
                if (p == 0) {
                    pk = (float4){pm[0], pm[1], pm[2], pm[3]};
                } else {
                    pk = *reinterpret_cast<float4*>(&pool_w[wv][m * 16 + kg * 4]);
                    pk.x += pm[0]; pk.y += pm[1]; pk.z += pm[2]; pk.w += pm[3];
                }
                *reinterpret_cast<float4*>(&pool_w[wv][m * 16 + kg * 4]) = pk;
            }
        }
    }
    __syncthreads();
    if (tid < 64) {
        float s = pool_w[0][tid] + pool_w[1][tid] + pool_w[2][tid] + pool_w[3][tid];
        atomicAdd(&pooled[img * 64 + tid], s);
    }
}

// ================= fused per-batch transformer (1024 threads = 16 waves) =================
template<int MT, int NT, int KS>
__device__ __forceinline__ void mfma_gemm(
    const unsigned short* A, int lda, int m0,
    const unsigned short* B, int ldb, int nt0,
    fx4 (&acc)[MT][NT], int lane)
{
    const int lo = lane & 15, kg = lane >> 4;
    #pragma unroll
    for (int ks = 0; ks < KS; ++ks) {
        const int k = ks * 32 + kg * 8;
        bf16x8 af[MT];
        #pragma unroll
        for (int m = 0; m < MT; ++m)
            af[m] = *reinterpret_cast<const bf16x8*>(A + (size_t)((m0 + m) * 16 + lo) * lda + k);
        #pragma unroll
        for (int n = 0; n < NT; ++n) {
            bf16x8 bf = *reinterpret_cast<const bf16x8*>(B + (size_t)((nt0 + n) * 16 + lo) * ldb + k);
            #pragma unroll
            for (int m = 0; m < MT; ++m)
                acc[m][n] = __builtin_amdgcn_mfma_f32_16x16x32_bf16(af[m], bf, acc[m][n], 0, 0, 0);
        }
    }
}

// 16-wave variant: each wave handles 2 rows
__device__ __forceinline__ void ln_update(
    const float* outs /*[32][257] LDS*/, float* hs, unsigned short* hs_b,
    const float* gs, const float* gb, bool resid, int w, int lane)
{
    #pragma unroll
    for (int i = 0; i < 2; ++i) {
        int r = w * 2 + i;
        float x[4], s = 0.f, q = 0.f;
        #pragma unroll
        for (int j = 0; j < 4; ++j) {
            x[j] = outs[r * 257 + lane + 64 * j];
            s += x[j]; q += x[j] * x[j];
        }
        #pragma unroll
        for (int off = 1; off < 64; off <<= 1) {
            s += __shfl_xor(s, off);
            q += __shfl_xor(q, off);
        }
        float mn = s * (1.f / 256.f);
        float inv = rsqrtf(q * (1.f / 256.f) - mn * mn + LN_EPS);
        #pragma unroll
        for (int j = 0; j < 4; ++j) {
            int c = lane + 64 * j;
            float nv = (x[j] - mn) * inv * gs[c] + gb[c];
            if (resid) nv += hs[r * 256 + c];
            hs[r * 256 + c] = nv;
            hs_b[r * 264 + c] = f2bf(nv);
        }
    }
}

__global__ __launch_bounds__(1024) void k_xformer(
    const float* __restrict__ pooled, const float* __restrict__ padf,
    const unsigned short* __restrict__ wpk,
    const float* __restrict__ pb, const float* __restrict__ lps, const float* __restrict__ lpb,
    const float* __restrict__ qkvb, const float* __restrict__ obv,
    const float* __restrict__ las, const float* __restrict__ lab,
    const float* __restrict__ lms, const float* __restrict__ lmb,
    const float* __restrict__ hb, float* __restrict__ out)
{
    __shared__ __align__(16) char smem[124032];
    float* hs = (float*)(smem);
    unsigned short* hs_b = (unsigned short*)(smem + 32768);
    unsigned short* R1 = (unsigned short*)(smem + 49664);
    unsigned short* q_s = R1;                   // per-head stride 2304 elems
    unsigned short* k_s = R1 + 9216;
    unsigned short* us_b = R1;                  // [32][520]
    unsigned short* v_cm = (unsigned short*)(smem + 86528);    // [4][64][40], head stride 2560
    unsigned short* ys_b = (unsigned short*)(smem + 107008);   // [32][264]
    float* outs = (float*)(smem + 86528);       // [32][257]
    unsigned short* pool_b = (unsigned short*)(smem + 86528);  // [32][72]
    float* padc = (float*)(smem + 123904);

    const int b = blockIdx.x, t = threadIdx.x;
    const int w = t >> 6, lane = t & 63, lo = lane & 15, kg = lane >> 4;

    // ---- P0: load pad flags + pooled (mean) ----
    if (t < 32) padc[t] = padf[b * 32 + t];
    for (int i = t; i < 2048; i += 1024) {
        int r = i >> 6, k = i & 63;
        pool_b[r * 72 + k] = f2bf(pooled[((size_t)b * 32 + r) * 64 + k] * (1.f / 7056.f));
    }
    __syncthreads();

    // ---- P1: proj (64->256) + bias + LN -> hs ----
    {
        fx4 acc[1][2];
        acc[0][0] = (fx4){0.f, 0.f, 0.f, 0.f};
        acc[0][1] = (fx4){0.f, 0.f, 0.f, 0.f};
        int m0 = w & 1, nt0 = (w >> 1) * 2;
        mfma_gemm<1, 2, 2>(pool_b, 72, m0, wpk + 1048576, 64, nt0, acc, lane);
        __syncthreads();   // pool_b dead; outs aliases it
        #pragma unroll
        for (int n = 0; n < 2; ++n) {
            int c = (nt0 + n) * 16 + lo;
            float bias = pb[c];
            #pragma unroll
            for (int rg = 0; rg < 4; ++rg)
                outs[(m0 * 16 + kg * 4 + rg) * 257 + c] = acc[0][n][rg] + bias;
        }
        __syncthreads();
        ln_update(outs, hs, hs_b, lps, lpb, false, w, lane);
        __syncthreads();
    }

    // ---- transformer layers ----
    for (int l = 0; l < 2; ++l) {
        const unsigned short* wq = wpk + (size_t)l * 196608;
        const unsigned short* wo = wpk + 393216 + (size_t)l * 65536;
        const unsigned short* wu = wpk + 524288 + (size_t)l * 131072;
        const unsigned short* wd = wpk + 786432 + (size_t)l * 131072;

        // qkv (256 -> 768) + bias + RoPE -> q_s, k_s, v_cm
        {
            fx4 acc[2][3];
            #pragma unroll
            for (int m = 0; m < 2; ++m)
                #pragma unroll
                for (int n = 0; n < 3; ++n) acc[m][n] = (fx4){0.f, 0.f, 0.f, 0.f};
            int nt0 = w * 3;
            mfma_gemm<2, 3, 8>(hs_b, 264, 0, wq, 256, nt0, acc, lane);
            #pragma unroll
            for (int n = 0; n < 3; ++n) {
                int c = (nt0 + n) * 16 + lo;
                int kind = c >> 8, cl = c & 255, h = cl >> 6, d = cl & 63;
                float bias = qkvb[l * 768 + c];
                if (kind < 2) {
                    int j = d >> 1;
                    float freq = exp2f(-(float)j * 0.41524101186f);
                    unsigned short* dst = (kind ? k_s : q_s) + h * 2304;
                    #pragma unroll
                    for (int m = 0; m < 2; ++m)
                        #pragma unroll
                        for (int rg = 0; rg < 4; ++rg) {
                            float val = acc[m][n][rg] + bias;
                            float prt = __shfl_xor(val, 1);
                            int r = m * 16 + kg * 4 + rg;
                            float sn, cs;
                            __sincosf((float)r * freq, &sn, &cs);
                            float rv = (d & 1) ? (val * cs + prt * sn) : (val * cs - prt * sn);
                            dst[r * 72 + d] = f2bf(rv);
                        }
                } else {
                    #pragma unroll
                    for (int m = 0; m < 2; ++m)
                        #pragma unroll
                        for (int rg = 0; rg < 4; ++rg) {
                            int r = m * 16 + kg * 4 + rg;
                            v_cm[(h * 64 + d) * 40 + r] = f2bf(acc[m][n][rg] + bias);
                        }
                }
            }
            __syncthreads();
        }

        // scores = QK^T * scale, mask, softmax -> pa (aliases q_s); 8 waves
        {
            fx4 sc[1][2];
            sc[0][0] = (fx4){0.f, 0.f, 0.f, 0.f};
            sc[0][1] = (fx4){0.f, 0.f, 0.f, 0.f};
            int h = w >> 1, mt = w & 1;
            if (w < 8)
                mfma_gemm<1, 2, 2>(q_s + h * 2304, 72, mt, k_s + h * 2304, 72, 0, sc, lane);
            __syncthreads();    // all q_s reads done before pa overwrites
            if (w < 8) {
                unsigned short* pa = R1 + h * 2304;   // [32][40]
                float pad0 = padc[lo], pad1 = padc[16 + lo];
                #pragma unroll
                for (int rg = 0; rg < 4; ++rg) {
                    int qr = mt * 16 + kg * 4 + rg;
                    float v0 = (lo <= qr && pad0 != 0.f) ? sc[0][0][rg] * 0.125f : -1e9f;
                    float v1 = ((16 + lo) <= qr && pad1 != 0.f) ? sc[0][1][rg] * 0.125f : -1e9f;
                    float mx = fmaxf(v0, v1);
                    #pragma unroll
                    for (int off = 1; off < 16; off <<= 1) mx = fmaxf(mx, __shfl_xor(mx, off));
                    float e0 = __expf(v0 - mx), e1 = __expf(v1 - mx);
                    float sm = e0 + e1;
                    #pragma unroll
                    for (int off = 1; off < 16; off <<= 1) sm += __shfl_xor(sm, off);
                    float inv = 1.f / sm;
                    pa[qr * 40 + lo] = f2bf(e0 * inv);
                    pa[qr * 40 + 16 + lo] = f2bf(e1 * inv);
                }
            }
            __syncthreads();
        }

        // y = P @ V -> ys_b; 16 waves: (h, mt, n-half)
        {
            int h = w >> 2, mt = (w >> 1) & 1, nh = w & 1;
            fx4 yv[1][2];
            yv[0][0] = (fx4){0.f, 0.f, 0.f, 0.f};
            yv[0][1] = (fx4){0.f, 0.f, 0.f, 0.f};
            mfma_gemm<1, 2, 1>(R1 + h * 2304, 40, mt, v_cm + h * 2560, 40, nh * 2, yv, lane);
            #pragma unroll
            for (int n = 0; n < 2; ++n) {
                int d = (nh * 2 + n) * 16 + lo;
                #pragma unroll
                for (int rg = 0; rg < 4; ++rg)
                    ys_b[(mt * 16 + kg * 4 + rg) * 264 + h * 64 + d] = f2bf(yv[0][n][rg]);
            }
            __syncthreads();
        }

        // out-proj (256->256) + bias + pad-mask -> outs; LN + residual -> hs
        {
            fx4 ac[2][1];
            ac[0][0] = (fx4){0.f, 0.f, 0.f, 0.f};
            ac[1][0] = (fx4){0.f, 0.f, 0.f, 0.f};
            mfma_gemm<2, 1, 8>(ys_b, 264, 0, wo, 256, w, ac, lane);
            __syncthreads();   // ys_b/v_cm dead; outs aliases them
            {
                int c = w * 16 + lo;
                float bias = obv[l * 256 + c];
                #pragma unroll
                for (int m = 0; m < 2; ++m)
                    #pragma unroll
                    for (int rg = 0; rg < 4; ++rg) {
                        int r = m * 16 + kg * 4 + rg;
                        outs[r * 257 + c] = (ac[m][0][rg] + bias) * padc[r];
                    }
            }
            __syncthreads();
            ln_update(outs, hs, hs_b, las + l * 256, lab + l * 256, true, w, lane);
            __syncthreads();
        }

        // mlp up (256->512) + ReLU -> us_b
        {
            fx4 au[2][2];
            #pragma unroll
            for (int m = 0; m < 2; ++m) { au[m][0] = (fx4){0.f,0.f,0.f,0.f}; au[m][1] = (fx4){0.f,0.f,0.f,0.f}; }
            int nt0 = w * 2;
            mfma_gemm<2, 2, 8>(hs_b, 264, 0, wu, 256, nt0, au, lane);
            #pragma unroll
            for (int n = 0; n < 2; ++n) {
                int c = (nt0 + n) * 16 + lo;
                #pragma unroll
                for (int m = 0; m < 2; ++m)
                    #pragma unroll
                    for (int rg = 0; rg < 4; ++rg)
                        us_b[(m * 16 + kg * 4 + rg) * 520 + c] = f2bf(fmaxf(au[m][n][rg], 0.f));
            }
            __syncthreads();
        }

        // mlp down (512->256) -> outs; LN + residual -> hs
        {
            fx4 ad[2][1];
            ad[0][0] = (fx4){0.f, 0.f, 0.f, 0.f};
            ad[1][0] = (fx4){0.f, 0.f, 0.f, 0.f};
            mfma_gemm<2, 1, 16>(us_b, 520, 0, wd, 512, w, ad, lane);
            {
                int c = w * 16 + lo;
                #pragma unroll
                for (int m = 0; m < 2; ++m)
                    #pragma unroll
                    for (int rg = 0; rg < 4; ++rg)
                        outs[(m * 16 + kg * 4 + rg) * 257 + c] = ad[m][0][rg];
            }
            __syncthreads();
            ln_update(outs, hs, hs_b, lms + l * 256, lmb + l * 256, true, w, lane);
            __syncthreads();
        }
    }

    // ---- head (256->18) via MFMA (hwb bf16 [32][256] at wpk+1064960, n>=18 zero) ----
    if (w < 4) {
        int mt = w >> 1, nt = w & 1;
        fx4 hd[1][1];
        hd[0][0] = (fx4){0.f, 0.f, 0.f, 0.f};
        mfma_gemm<1, 1, 8>(hs_b, 264, mt, wpk + 1064960, 256, nt, hd, lane);
        int cc = nt * 16 + lo;
        if (cc < 18) {
            float bias = hb[cc];
            #pragma unroll
            for (int rg = 0; rg < 4; ++rg)
                out[((size_t)b * 32 + mt * 16 + kg * 4 + rg) * 18 + cc] = hd[0][0][rg] + bias;
        }
    }
}

extern "C" void kernel_launch(void* const* d_in, const int* in_sizes, int n_in,
                              void* d_out, int out_size, void* d_ws, size_t ws_size,
                              hipStream_t stream)
{
    (void)in_sizes; (void)n_in; (void)out_size; (void)ws_size;
    const float* x   = (const float*)d_in[0];
    const unsigned char* pad = (const unsigned char*)d_in[1];
    const float* c0w = (const float*)d_in[2];
    const float* c0b = (const float*)d_in[3];
    const float* l0s = (const float*)d_in[4];
    const float* l0b = (const float*)d_in[5];
    const float* c1w = (const float*)d_in[6];
    const float* c1b = (const float*)d_in[7];
    const float* l1s = (const float*)d_in[8];
    const float* l1b = (const float*)d_in[9];
    const float* pw  = (const float*)d_in[10];
    const float* pb  = (const float*)d_in[11];
    const float* lps = (const float*)d_in[12];
    const float* lpb = (const float*)d_in[13];
    const float* qkvw = (const float*)d_in[14];
    const float* qkvb = (const float*)d_in[15];
    const float* ow  = (const float*)d_in[16];
    const float* obv = (const float*)d_in[17];
    const float* las = (const float*)d_in[18];
    const float* lab = (const float*)d_in[19];
    const float* upw = (const float*)d_in[20];
    const float* dww = (const float*)d_in[21];
    const float* lms = (const float*)d_in[22];
    const float* lmb = (const float*)d_in[23];
    const float* hw  = (const float*)d_in[24];
    const float* hb  = (const float*)d_in[25];
    float* out = (float*)d_out;

    char* ws = (char*)d_ws;
    size_t off = 0;
    auto alloc = [&](size_t bytes) -> void* {
        void* p = ws + off;
        off = (off + bytes + 255) & ~(size_t)255;
        return p;
    };
    unsigned short* wtb = (unsigned short*)alloc(20480 * 2);
    unsigned short* wpk = (unsigned short*)alloc((size_t)1073152 * 2);
    float* pooled = (float*)alloc(512 * 64 * 4);
    float* padf   = (float*)alloc(512 * 4);

    k_prep<<<4402, 256, 0, stream>>>(pad, c1w, c0w, qkvw, ow, upw, dww, pw, hw,
                                     padf, wtb, wpk, pooled);
    k_conv1<<<14336, 256, 0, stream>>>(x, wtb, c0b, l0s, l0b, c1b, l1s, l1b, pooled);
    k_xformer<<<16, 1024, 0, stream>>>(pooled, padf, wpk, pb, lps, lpb,
                                       qkvb, obv, las, lab, lms, lmb, hb, out);
}

// Round 13
// 350.324 us; speedup vs baseline: 1.2931x; 1.2931x over previous
//
#include <hip/hip_runtime.h>
#include <hip/hip_bf16.h>

#define LN_EPS 1e-6f

typedef __attribute__((ext_vector_type(8))) short bf16x8;
typedef __attribute__((ext_vector_type(4))) float fx4;

struct U8 { union { bf16x8 v; uint2 p[2]; }; };

__device__ __forceinline__ unsigned short f2bf(float f) {
    union { __hip_bfloat16 b; unsigned short u; } cv;
    cv.b = __float2bfloat16(f);
    return cv.u;
}

// ---------- fused prep: pad detect + pooled memset + conv weight repack + tail weight pack ----------
// block 0: pad; blocks [1,129): pooled=0; [129,209): wtb; [209,4402): wpk
// wtb[0..18432): conv1 (3,3,32,64) -> [tap][co][kg][j] bf16
// wtb[18432..20480): conv0 (3,3,4,32) -> wc0[ch 32][k 64] bf16, k=(tap<<2)|ci, zero-padded k>=36
// wpk (elems): qkv 2*768*256 | out 2*256*256 | up 2*512*256 | down 2*256*512 | proj 256*64 | head 32*256
__global__ __launch_bounds__(256) void k_prep(
    const unsigned char* __restrict__ pad,
    const float* __restrict__ w1, const float* __restrict__ w0,
    const float* __restrict__ qkvw, const float* __restrict__ ow,
    const float* __restrict__ upw, const float* __restrict__ dww,
    const float* __restrict__ pw, const float* __restrict__ hw,
    float* __restrict__ padf, unsigned short* __restrict__ wtb,
    unsigned short* __restrict__ wpk, float* __restrict__ pooled)
{
    __shared__ int cnt;
    const int bid = blockIdx.x, t = threadIdx.x;
    if (bid == 0) {
        if (t == 0) cnt = 0;
        __syncthreads();
        int c = 0;
        if (pad[t]) c++;
        if (pad[t + 256]) c++;
        if (c) atomicAdd(&cnt, c);
        __syncthreads();
        bool asU8 = cnt > 256;
        for (int i = t; i < 512; i += 256)
            padf[i] = asU8 ? (pad[i] ? 1.f : 0.f) : (((const int*)pad)[i] ? 1.f : 0.f);
    } else if (bid < 129) {
        pooled[(bid - 1) * 256 + t] = 0.f;             // 32768 exactly
    } else if (bid < 209) {
        int idx = (bid - 129) * 256 + t;               // 20480 exactly
        if (idx < 18432) {
            int j  = idx & 7;
            int kg = (idx >> 3) & 3;
            int co = (idx >> 5) & 63;
            int tp = idx >> 11;
            wtb[idx] = f2bf(w1[((size_t)tp * 32 + kg * 8 + j) * 64 + co]);
        } else {
            int r = idx - 18432;
            int ch = r >> 6, k = r & 63;
            float v = 0.f;
            if (k < 36) v = w0[(size_t)k * 32 + ch];
            wtb[idx] = f2bf(v);
        }
    } else {
        int idx = (bid - 209) * 256 + t;
        if (idx >= 1073152) return;
        float v;
        if (idx < 393216) {
            int l = idx / 196608, rm = idx % 196608, n = rm >> 8, k = rm & 255;
            v = qkvw[((size_t)l * 256 + k) * 768 + n];
        } else if (idx < 524288) {
            int r = idx - 393216, l = r >> 16, rm = r & 65535, n = rm >> 8, k = rm & 255;
            v = ow[((size_t)l * 256 + k) * 256 + n];
        } else if (idx < 786432) {
            int r = idx - 524288, l = r >> 17, rm = r & 131071, n = rm >> 8, k = rm & 255;
            v = upw[((size_t)l * 256 + k) * 512 + n];
        } else if (idx < 1048576) {
            int r = idx - 786432, l = r >> 17, rm = r & 131071, n = rm >> 9, k = rm & 511;
            v = dww[((size_t)l * 512 + k) * 256 + n];
        } else if (idx < 1064960) {
            int r = idx - 1048576, n = r >> 6, k = r & 63;
            v = pw[k * 256 + n];
        } else {
            int r = idx - 1064960, n = r >> 8, k = r & 255;
            v = (n < 18) ? hw[(size_t)k * 18 + n] : 0.f;
        }
        wpk[idx] = f2bf(v);
    }
}

// ---------- fused conv0+conv1 + LN + ReLU + mean-pool (R11 verified-best build) ----------
// Block: one image x 6 output rows (halo redundancy 8/6).
// Phase 0: stage x rows y0-2..y0+7 bf16 -> xs[10][86][4] (zero-padded halo).
// Phase 1 (swapped): conv0 MFMA over 672 px (8 rows) -> At[4][8][86][8]; incremental r5/col.
// Phase 2+3: two 256-px passes of conv1 MFMA + LN(64) + ReLU + pool; epilogue streamed per m.
// R8 lesson: pool must not be live across MFMA. R9 lesson: stream epilogue per m-tile.
// R12 lesson: (256,4)+acc-split doubles Wf loads and loses more than occupancy gains.
__global__ __launch_bounds__(256, 3) void k_conv1(
    const float* __restrict__ x, const unsigned short* __restrict__ wtb,
    const float* __restrict__ c0b, const float* __restrict__ l0s, const float* __restrict__ l0b,
    const float* __restrict__ bias, const float* __restrict__ lns, const float* __restrict__ lnb,
    float* __restrict__ pooled)
{
    __shared__ __align__(16) unsigned short At[4][8][86][8];   // 44032 B
    __shared__ __align__(16) unsigned short xs[10][86][4];     // 6880 B
    __shared__ __align__(16) float pool_w[4][64];
    const int tid = threadIdx.x;
    const int img = blockIdx.x / 14;
    const int rg  = blockIdx.x - img * 14;
    const int y0  = rg * 6;

    const int lane = tid & 63;
    const int wv = tid >> 6;
    const int lo = lane & 15;
    const int kg = lane >> 4;

    // ---- phase 0: stage x (10 rows, bf16, halo-padded) + zero At/xs halo cols ----
    if (tid >= 128 && tid < 192) {
        int z = tid - 128;
        int zk = z >> 4, rem = z & 15, zr = rem >> 1, side = rem & 1;
        *reinterpret_cast<uint4*>(&At[zk][zr][side ? 85 : 0][0]) = (uint4){0, 0, 0, 0};
    }
    if (tid >= 104 && tid < 124) {
        int z = tid - 104, row = z >> 1, side = z & 1;
        *reinterpret_cast<uint2*>(&xs[row][side ? 85 : 0][0]) = (uint2){0, 0};
    }
    for (int i = tid; i < 840; i += 256) {
        int row = i / 84, c = i - row * 84;
        int gy = y0 - 2 + row;
        float4 v = (float4){0.f, 0.f, 0.f, 0.f};
        if (gy >= 0 && gy < 84)
            v = *reinterpret_cast<const float4*>(x + ((size_t)img * 7056 + gy * 84 + c) * 4);
        unsigned l32 = (unsigned)f2bf(v.x) | ((unsigned)f2bf(v.y) << 16);
        unsigned h32 = (unsigned)f2bf(v.z) | ((unsigned)f2bf(v.w) << 16);
        *reinterpret_cast<uint2*>(&xs[row][c + 1][0]) = (uint2){l32, h32};
    }
    __syncthreads();

    // ---- phase 1: conv0 via MFMA (operand-swapped) -> At (8 rows, 672 px, 42 tiles) ----
    {
        const unsigned short* wc0 = wtb + 18432;
        bf16x8 W0[2], W1[2];
        #pragma unroll
        for (int m = 0; m < 2; ++m) {
            W0[m] = *reinterpret_cast<const bf16x8*>(wc0 + (m * 16 + lo) * 64 + kg * 8);
            W1[m] = *reinterpret_cast<const bf16x8*>(wc0 + (m * 16 + lo) * 64 + 32 + kg * 8);
        }
        float cb[2][4], sg[2][4], bg[2][4];
        #pragma unroll
        for (int m = 0; m < 2; ++m)
            #pragma unroll
            for (int r = 0; r < 4; ++r) {
                int c = m * 16 + kg * 4 + r;
                cb[m][r] = c0b[c]; sg[m][r] = l0s[c]; bg[m][r] = l0b[c];
            }
        const int t0 = 2 * kg, t1 = 2 * kg + 1;
        const int dy0 = t0 / 3, dx0 = t0 % 3, dy1 = t1 / 3, dx1 = t1 % 3;
        const unsigned short* xsb = &xs[0][0][0];

        // incremental pixel addressing: px = it*64 + wv*16 + lo; step 64 < 84 -> single wrap
        int r5 = 0, col = wv * 16 + lo;
        for (int it = 0; it < 11; ++it) {
            int tb = it * 4 + wv;
            if (tb >= 42) break;
            U8 a0u, a1u;
            a0u.p[0] = *reinterpret_cast<const uint2*>(xsb + ((r5 + dy0) * 86 + col + dx0) * 4);
            a0u.p[1] = *reinterpret_cast<const uint2*>(xsb + ((r5 + dy1) * 86 + col + dx1) * 4);
            if (kg == 0)
                a1u.p[0] = *reinterpret_cast<const uint2*>(xsb + ((r5 + 2) * 86 + col + 2) * 4);
            else
                a1u.p[0] = (uint2){0, 0};
            a1u.p[1] = (uint2){0, 0};

            fx4 c2[2];
            c2[0] = (fx4){0.f, 0.f, 0.f, 0.f};
            c2[1] = (fx4){0.f, 0.f, 0.f, 0.f};
            c2[0] = __builtin_amdgcn_mfma_f32_16x16x32_bf16(W0[0], a0u.v, c2[0], 0, 0, 0);
            c2[0] = __builtin_amdgcn_mfma_f32_16x16x32_bf16(W1[0], a1u.v, c2[0], 0, 0, 0);
            c2[1] = __builtin_amdgcn_mfma_f32_16x16x32_bf16(W0[1], a0u.v, c2[1], 0, 0, 0);
            c2[1] = __builtin_amdgcn_mfma_f32_16x16x32_bf16(W1[1], a1u.v, c2[1], 0, 0, 0);

            float v[2][4], s = 0.f, q = 0.f;
            #pragma unroll
            for (int m = 0; m < 2; ++m)
                #pragma unroll
                for (int r = 0; r < 4; ++r) {
                    v[m][r] = c2[m][r] + cb[m][r];
                    s += v[m][r]; q += v[m][r] * v[m][r];
                }
            s += __shfl_xor(s, 16); q += __shfl_xor(q, 16);
            s += __shfl_xor(s, 32); q += __shfl_xor(q, 32);
            float mn = s * (1.f / 32.f);
            float inv = rsqrtf(q * (1.f / 32.f) - mn * mn + LN_EPS);

            int yA = y0 - 1 + r5;
            bool gv = (unsigned)yA < 84u;
            #pragma unroll
            for (int m = 0; m < 2; ++m) {
                uint2 pk = (uint2){0, 0};
                if (gv) {
                    unsigned short o0 = f2bf(fmaxf((v[m][0] - mn) * inv * sg[m][0] + bg[m][0], 0.f));
                    unsigned short o1 = f2bf(fmaxf((v[m][1] - mn) * inv * sg[m][1] + bg[m][1], 0.f));
                    unsigned short o2 = f2bf(fmaxf((v[m][2] - mn) * inv * sg[m][2] + bg[m][2], 0.f));
                    unsigned short o3 = f2bf(fmaxf((v[m][3] - mn) * inv * sg[m][3] + bg[m][3], 0.f));
                    pk.x = (unsigned)o0 | ((unsigned)o1 << 16);
                    pk.y = (unsigned)o2 | ((unsigned)o3 << 16);
                }
                *reinterpret_cast<uint2*>(&At[2 * m + (kg >> 1)][r5][col + 1][(kg & 1) * 4]) = pk;
            }
            col += 64;
            if (col >= 84) { col -= 84; r5 += 1; }
        }
    }
    __syncthreads();

    // ---- phases 2+3: two 256-pixel passes; epilogue streamed per m-tile ----
    const unsigned short* Abase = &At[0][0][0][0];
    #pragma unroll
    for (int p = 0; p < 2; ++p) {
        const int pbase = p * 256;
        int abase[4];
        #pragma unroll
        for (int n = 0; n < 4; ++n) {
            int pl = pbase + wv * 64 + n * 16 + lo;
            if (pl > 503) pl = 503;
            int rl = pl / 84;
            int c = pl - rl * 84;
            abase[n] = ((kg * 8 + rl) * 86 + c) * 8;
        }

        fx4 acc[4][4];   // acc[m][n]: channels m*16+kg*4+rg, pixel n*16+lo
        #pragma unroll
        for (int m = 0; m < 4; ++m)
            #pragma unroll
            for (int n = 0; n < 4; ++n) acc[m][n] = (fx4){0.f, 0.f, 0.f, 0.f};

        #pragma unroll
        for (int dy = 0; dy < 3; ++dy) {
            #pragma unroll
            for (int dx = 0; dx < 3; ++dx) {
                const int t = dy * 3 + dx;
                bf16x8 Wf[4];
                #pragma unroll
                for (int m = 0; m < 4; ++m)
                    Wf[m] = *reinterpret_cast<const bf16x8*>(
                        wtb + (size_t)((t * 64 + m * 16 + lo) * 4 + kg) * 8);
                #pragma unroll
                for (int n = 0; n < 4; ++n) {
                    bf16x8 Pf = *reinterpret_cast<const bf16x8*>(Abase + abase[n] + (dy * 86 + dx) * 8);
                    #pragma unroll
                    for (int m = 0; m < 4; ++m)
                        acc[m][n] = __builtin_amdgcn_mfma_f32_16x16x32_bf16(Wf[m], Pf, acc[m][n], 0, 0, 0);
                }
            }
        }

        // stats pass: bias (in-place) + per-pixel sums
        float s4[4] = {0.f, 0.f, 0.f, 0.f}, q4[4] = {0.f, 0.f, 0.f, 0.f};
        #pragma unroll
        for (int m = 0; m < 4; ++m) {
            float4 cbv = *reinterpret_cast<const float4*>(bias + m * 16 + kg * 4);
            #pragma unroll
            for (int n = 0; n < 4; ++n)
                #pragma unroll
                for (int r = 0; r < 4; ++r) {
                    float val = acc[m][n][r] + (&cbv.x)[r];
                    acc[m][n][r] = val;
                    s4[n] += val; q4[n] += val * val;
                }
        }
        float mn4[4], iv4[4], pval[4];
        #pragma unroll
        for (int n = 0; n < 4; ++n) {
            float s = s4[n], q = q4[n];
            s += __shfl_xor(s, 16); q += __shfl_xor(q, 16);
            s += __shfl_xor(s, 32); q += __shfl_xor(q, 32);
            float mn = s * (1.f / 64.f);
            mn4[n] = mn;
            iv4[n] = rsqrtf(q * (1.f / 64.f) - mn * mn + LN_EPS);
            pval[n] = (pbase + wv * 64 + n * 16 + lo < 504) ? 1.f : 0.f;
        }
        // streamed per-m: normalize + pool + butterfly + LDS RMW; pm dies each m
        #pragma unroll
        for (int m = 0; m < 4; ++m) {
            float4 sgv = *reinterpret_cast<const float4*>(lns + m * 16 + kg * 4);
            float4 bgv = *reinterpret_cast<const float4*>(lnb + m * 16 + kg * 4);
            float pm[4] = {0.f, 0.f, 0.f, 0.f};
            #pragma unroll
            for (int n = 0; n < 4; ++n)
                #pragma unroll
                for (int r = 0; r < 4; ++r) {
                    float o = fmaxf((acc[m][n][r] - mn4[n]) * iv4[n] * (&sgv.x)[r] + (&bgv.x)[r], 0.f);
                    pm[r] = fmaf(o, pval[n], pm[r]);
                }
            #pragma unroll
            for (int off = 1; off < 16; off <<= 1)
                #pragma unroll
                for (int r = 0; r < 4; ++r)
                    pm[r] += __shfl_xor(pm[r], off);
            if (lo == 0) {
                float4 pk;
                if (p == 0) {
                    pk = (float4){pm[0], pm[1], pm[2], pm[3]};
                } else {
                    pk = *reinterpret_cast<float4*>(&pool_w[wv][m * 16 + kg * 4]);
                    pk.x += pm[0]; pk.y += pm[1]; pk.z += pm[2]; pk.w += pm[3];
                }
                *reinterpret_cast<float4*>(&pool_w[wv][m * 16 + kg * 4]) = pk;
            }
        }
    }
    __syncthreads();
    if (tid < 64) {
        float s = pool_w[0][tid] + pool_w[1][tid] + pool_w[2][tid] + pool_w[3][tid];
        atomicAdd(&pooled[img * 64 + tid], s);
    }
}

// ================= fused per-batch transformer (1024 threads = 16 waves) =================
template<int MT, int NT, int KS>
__device__ __forceinline__ void mfma_gemm(
    const unsigned short* A, int lda, int m0,
    const unsigned short* B, int ldb, int nt0,
    fx4 (&acc)[MT][NT], int lane)
{
    const int lo = lane & 15, kg = lane >> 4;
    #pragma unroll
    for (int ks = 0; ks < KS; ++ks) {
        const int k = ks * 32 + kg * 8;
        bf16x8 af[MT];
        #pragma unroll
        for (int m = 0; m < MT; ++m)
            af[m] = *reinterpret_cast<const bf16x8*>(A + (size_t)((m0 + m) * 16 + lo) * lda + k);
        #pragma unroll
        for (int n = 0; n < NT; ++n) {
            bf16x8 bf = *reinterpret_cast<const bf16x8*>(B + (size_t)((nt0 + n) * 16 + lo) * ldb + k);
            #pragma unroll
            for (int m = 0; m < MT; ++m)
                acc[m][n] = __builtin_amdgcn_mfma_f32_16x16x32_bf16(af[m], bf, acc[m][n], 0, 0, 0);
        }
    }
}

// 16-wave variant: each wave handles 2 rows
__device__ __forceinline__ void ln_update(
    const float* outs /*[32][257] LDS*/, float* hs, unsigned short* hs_b,
    const float* gs, const float* gb, bool resid, int w, int lane)
{
    #pragma unroll
    for (int i = 0; i < 2; ++i) {
        int r = w * 2 + i;
        float x[4], s = 0.f, q = 0.f;
        #pragma unroll
        for (int j = 0; j < 4; ++j) {
            x[j] = outs[r * 257 + lane + 64 * j];
            s += x[j]; q += x[j] * x[j];
        }
        #pragma unroll
        for (int off = 1; off < 64; off <<= 1) {
            s += __shfl_xor(s, off);
            q += __shfl_xor(q, off);
        }
        float mn = s * (1.f / 256.f);
        float inv = rsqrtf(q * (1.f / 256.f) - mn * mn + LN_EPS);
        #pragma unroll
        for (int j = 0; j < 4; ++j) {
            int c = lane + 64 * j;
            float nv = (x[j] - mn) * inv * gs[c] + gb[c];
            if (resid) nv += hs[r * 256 + c];
            hs[r * 256 + c] = nv;
            hs_b[r * 264 + c] = f2bf(nv);
        }
    }
}

__global__ __launch_bounds__(1024) void k_xformer(
    const float* __restrict__ pooled, const float* __restrict__ padf,
    const unsigned short* __restrict__ wpk,
    const float* __restrict__ pb, const float* __restrict__ lps, const float* __restrict__ lpb,
    const float* __restrict__ qkvb, const float* __restrict__ obv,
    const float* __restrict__ las, const float* __restrict__ lab,
    const float* __restrict__ lms, const float* __restrict__ lmb,
    const float* __restrict__ hb, float* __restrict__ out)
{
    __shared__ __align__(16) char smem[124032];
    float* hs = (float*)(smem);
    unsigned short* hs_b = (unsigned short*)(smem + 32768);
    unsigned short* R1 = (unsigned short*)(smem + 49664);
    unsigned short* q_s = R1;                   // per-head stride 2304 elems
    unsigned short* k_s = R1 + 9216;
    unsigned short* us_b = R1;                  // [32][520]
    unsigned short* v_cm = (unsigned short*)(smem + 86528);    // [4][64][40], head stride 2560
    unsigned short* ys_b = (unsigned short*)(smem + 107008);   // [32][264]
    float* outs = (float*)(smem + 86528);       // [32][257]
    unsigned short* pool_b = (unsigned short*)(smem + 86528);  // [32][72]
    float* padc = (float*)(smem + 123904);

    const int b = blockIdx.x, t = threadIdx.x;
    const int w = t >> 6, lane = t & 63, lo = lane & 15, kg = lane >> 4;

    // ---- P0: load pad flags + pooled (mean) ----
    if (t < 32) padc[t] = padf[b * 32 + t];
    for (int i = t; i < 2048; i += 1024) {
        int r = i >> 6, k = i & 63;
        pool_b[r * 72 + k] = f2bf(pooled[((size_t)b * 32 + r) * 64 + k] * (1.f / 7056.f));
    }
    __syncthreads();

    // ---- P1: proj (64->256) + bias + LN -> hs ----
    {
        fx4 acc[1][2];
        acc[0][0] = (fx4){0.f, 0.f, 0.f, 0.f};
        acc[0][1] = (fx4){0.f, 0.f, 0.f, 0.f};
        int m0 = w & 1, nt0 = (w >> 1) * 2;
        mfma_gemm<1, 2, 2>(pool_b, 72, m0, wpk + 1048576, 64, nt0, acc, lane);
        __syncthreads();   // pool_b dead; outs aliases it
        #pragma unroll
        for (int n = 0; n < 2; ++n) {
            int c = (nt0 + n) * 16 + lo;
            float bias = pb[c];
            #pragma unroll
            for (int rg = 0; rg < 4; ++rg)
                outs[(m0 * 16 + kg * 4 + rg) * 257 + c] = acc[0][n][rg] + bias;
        }
        __syncthreads();
        ln_update(outs, hs, hs_b, lps, lpb, false, w, lane);
        __syncthreads();
    }

    // ---- transformer layers ----
    for (int l = 0; l < 2; ++l) {
        const unsigned short* wq = wpk + (size_t)l * 196608;
        const unsigned short* wo = wpk + 393216 + (size_t)l * 65536;
        const unsigned short* wu = wpk + 524288 + (size_t)l * 131072;
        const unsigned short* wd = wpk + 786432 + (size_t)l * 131072;

        // qkv (256 -> 768) + bias + RoPE -> q_s, k_s, v_cm
        {
            fx4 acc[2][3];
            #pragma unroll
            for (int m = 0; m < 2; ++m)
                #pragma unroll
                for (int n = 0; n < 3; ++n) acc[m][n] = (fx4){0.f, 0.f, 0.f, 0.f};
            int nt0 = w * 3;
            mfma_gemm<2, 3, 8>(hs_b, 264, 0, wq, 256, nt0, acc, lane);
            #pragma unroll
            for (int n = 0; n < 3; ++n) {
                int c = (nt0 + n) * 16 + lo;
                int kind = c >> 8, cl = c & 255, h = cl >> 6, d = cl & 63;
                float bias = qkvb[l * 768 + c];
                if (kind < 2) {
                    int j = d >> 1;
                    float freq = exp2f(-(float)j * 0.41524101186f);
                    unsigned short* dst = (kind ? k_s : q_s) + h * 2304;
                    #pragma unroll
                    for (int m = 0; m < 2; ++m)
                        #pragma unroll
                        for (int rg = 0; rg < 4; ++rg) {
                            float val = acc[m][n][rg] + bias;
                            float prt = __shfl_xor(val, 1);
                            int r = m * 16 + kg * 4 + rg;
                            float sn, cs;
                            __sincosf((float)r * freq, &sn, &cs);
                            float rv = (d & 1) ? (val * cs + prt * sn) : (val * cs - prt * sn);
                            dst[r * 72 + d] = f2bf(rv);
                        }
                } else {
                    #pragma unroll
                    for (int m = 0; m < 2; ++m)
                        #pragma unroll
                        for (int rg = 0; rg < 4; ++rg) {
                            int r = m * 16 + kg * 4 + rg;
                            v_cm[(h * 64 + d) * 40 + r] = f2bf(acc[m][n][rg] + bias);
                        }
                }
            }
            __syncthreads();
        }

        // scores = QK^T * scale, mask, softmax -> pa (aliases q_s); 8 waves
        {
            fx4 sc[1][2];
            sc[0][0] = (fx4){0.f, 0.f, 0.f, 0.f};
            sc[0][1] = (fx4){0.f, 0.f, 0.f, 0.f};
            int h = w >> 1, mt = w & 1;
            if (w < 8)
                mfma_gemm<1, 2, 2>(q_s + h * 2304, 72, mt, k_s + h * 2304, 72, 0, sc, lane);
            __syncthreads();    // all q_s reads done before pa overwrites
            if (w < 8) {
                unsigned short* pa = R1 + h * 2304;   // [32][40]
                float pad0 = padc[lo], pad1 = padc[16 + lo];
                #pragma unroll
                for (int rg = 0; rg < 4; ++rg) {
                    int qr = mt * 16 + kg * 4 + rg;
                    float v0 = (lo <= qr && pad0 != 0.f) ? sc[0][0][rg] * 0.125f : -1e9f;
                    float v1 = ((16 + lo) <= qr && pad1 != 0.f) ? sc[0][1][rg] * 0.125f : -1e9f;
                    float mx = fmaxf(v0, v1);
                    #pragma unroll
                    for (int off = 1; off < 16; off <<= 1) mx = fmaxf(mx, __shfl_xor(mx, off));
                    float e0 = __expf(v0 - mx), e1 = __expf(v1 - mx);
                    float sm = e0 + e1;
                    #pragma unroll
                    for (int off = 1; off < 16; off <<= 1) sm += __shfl_xor(sm, off);
                    float inv = 1.f / sm;
                    pa[qr * 40 + lo] = f2bf(e0 * inv);
                    pa[qr * 40 + 16 + lo] = f2bf(e1 * inv);
                }
            }
            __syncthreads();
        }

        // y = P @ V -> ys_b; 16 waves: (h, mt, n-half)
        {
            int h = w >> 2, mt = (w >> 1) & 1, nh = w & 1;
            fx4 yv[1][2];
            yv[0][0] = (fx4){0.f, 0.f, 0.f, 0.f};
            yv[0][1] = (fx4){0.f, 0.f, 0.f, 0.f};
            mfma_gemm<1, 2, 1>(R1 + h * 2304, 40, mt, v_cm + h * 2560, 40, nh * 2, yv, lane);
            #pragma unroll
            for (int n = 0; n < 2; ++n) {
                int d = (nh * 2 + n) * 16 + lo;
                #pragma unroll
                for (int rg = 0; rg < 4; ++rg)
                    ys_b[(mt * 16 + kg * 4 + rg) * 264 + h * 64 + d] = f2bf(yv[0][n][rg]);
            }
            __syncthreads();
        }

        // out-proj (256->256) + bias + pad-mask -> outs; LN + residual -> hs
        {
            fx4 ac[2][1];
            ac[0][0] = (fx4){0.f, 0.f, 0.f, 0.f};
            ac[1][0] = (fx4){0.f, 0.f, 0.f, 0.f};
            mfma_gemm<2, 1, 8>(ys_b, 264, 0, wo, 256, w, ac, lane);
            __syncthreads();   // ys_b/v_cm dead; outs aliases them
            {
                int c = w * 16 + lo;
                float bias = obv[l * 256 + c];
                #pragma unroll
                for (int m = 0; m < 2; ++m)
                    #pragma unroll
                    for (int rg = 0; rg < 4; ++rg) {
                        int r = m * 16 + kg * 4 + rg;
                        outs[r * 257 + c] = (ac[m][0][rg] + bias) * padc[r];
                    }
            }
            __syncthreads();
            ln_update(outs, hs, hs_b, las + l * 256, lab + l * 256, true, w, lane);
            __syncthreads();
        }

        // mlp up (256->512) + ReLU -> us_b
        {
            fx4 au[2][2];
            #pragma unroll
            for (int m = 0; m < 2; ++m) { au[m][0] = (fx4){0.f,0.f,0.f,0.f}; au[m][1] = (fx4){0.f,0.f,0.f,0.f}; }
            int nt0 = w * 2;
            mfma_gemm<2, 2, 8>(hs_b, 264, 0, wu, 256, nt0, au, lane);
            #pragma unroll
            for (int n = 0; n < 2; ++n) {
                int c = (nt0 + n) * 16 + lo;
                #pragma unroll
                for (int m = 0; m < 2; ++m)
                    #pragma unroll
                    for (int rg = 0; rg < 4; ++rg)
                        us_b[(m * 16 + kg * 4 + rg) * 520 + c] = f2bf(fmaxf(au[m][n][rg], 0.f));
            }
            __syncthreads();
        }

        // mlp down (512->256) -> outs; LN + residual -> hs
        {
            fx4 ad[2][1];
            ad[0][0] = (fx4){0.f, 0.f, 0.f, 0.f};
            ad[1][0] = (fx4){0.f, 0.f, 0.f, 0.f};
            mfma_gemm<2, 1, 16>(us_b, 520, 0, wd, 512, w, ad, lane);
            {
                int c = w * 16 + lo;
                #pragma unroll
                for (int m = 0; m < 2; ++m)
                    #pragma unroll
                    for (int rg = 0; rg < 4; ++rg)
                        outs[(m * 16 + kg * 4 + rg) * 257 + c] = ad[m][0][rg];
            }
            __syncthreads();
            ln_update(outs, hs, hs_b, lms + l * 256, lmb + l * 256, true, w, lane);
            __syncthreads();
        }
    }

    // ---- head (256->18) via MFMA (hwb bf16 [32][256] at wpk+1064960, n>=18 zero) ----
    if (w < 4) {
        int mt = w >> 1, nt = w & 1;
        fx4 hd[1][1];
        hd[0][0] = (fx4){0.f, 0.f, 0.f, 0.f};
        mfma_gemm<1, 1, 8>(hs_b, 264, mt, wpk + 1064960, 256, nt, hd, lane);
        int cc = nt * 16 + lo;
        if (cc < 18) {
            float bias = hb[cc];
            #pragma unroll
            for (int rg = 0; rg < 4; ++rg)
                out[((size_t)b * 32 + mt * 16 + kg * 4 + rg) * 18 + cc] = hd[0][0][rg] + bias;
        }
    }
}

extern "C" void kernel_launch(void* const* d_in, const int* in_sizes, int n_in,
                              void* d_out, int out_size, void* d_ws, size_t ws_size,
                              hipStream_t stream)
{
    (void)in_sizes; (void)n_in; (void)out_size; (void)ws_size;
    const float* x   = (const float*)d_in[0];
    const unsigned char* pad = (const unsigned char*)d_in[1];
    const float* c0w = (const float*)d_in[2];
    const float* c0b = (const float*)d_in[3];
    const float* l0s = (const float*)d_in[4];
    const float* l0b = (const float*)d_in[5];
    const float* c1w = (const float*)d_in[6];
    const float* c1b = (const float*)d_in[7];
    const float* l1s = (const float*)d_in[8];
    const float* l1b = (const float*)d_in[9];
    const float* pw  = (const float*)d_in[10];
    const float* pb  = (const float*)d_in[11];
    const float* lps = (const float*)d_in[12];
    const float* lpb = (const float*)d_in[13];
    const float* qkvw = (const float*)d_in[14];
    const float* qkvb = (const float*)d_in[15];
    const float* ow  = (const float*)d_in[16];
    const float* obv = (const float*)d_in[17];
    const float* las = (const float*)d_in[18];
    const float* lab = (const float*)d_in[19];
    const float* upw = (const float*)d_in[20];
    const float* dww = (const float*)d_in[21];
    const float* lms = (const float*)d_in[22];
    const float* lmb = (const float*)d_in[23];
    const float* hw  = (const float*)d_in[24];
    const float* hb  = (const float*)d_in[25];
    float* out = (float*)d_out;

    char* ws = (char*)d_ws;
    size_t off = 0;
    auto alloc = [&](size_t bytes) -> void* {
        void* p = ws + off;
        off = (off + bytes + 255) & ~(size_t)255;
        return p;
    };
    unsigned short* wtb = (unsigned short*)alloc(20480 * 2);
    unsigned short* wpk = (unsigned short*)alloc((size_t)1073152 * 2);
    float* pooled = (float*)alloc(512 * 64 * 4);
    float* padf   = (float*)alloc(512 * 4);

    k_prep<<<4402, 256, 0, stream>>>(pad, c1w, c0w, qkvw, ow, upw, dww, pw, hw,
                                     padf, wtb, wpk, pooled);
    k_conv1<<<7168, 256, 0, stream>>>(x, wtb, c0b, l0s, l0b, c1b, l1s, l1b, pooled);
    k_xformer<<<16, 1024, 0, stream>>>(pooled, padf, wpk, pb, lps, lpb,
                                       qkvb, obv, las, lab, lms, lmb, hb, out);
}